// Round 8
// baseline (2201.145 us; speedup 1.0000x reference)
//
#include <hip/hip_runtime.h>
#include <hip/hip_bf16.h>
#include <stdint.h>

// Problem constants
#define KVOL   27
#define MPAIRS 150000
#define NROWS  200000            // N_IN == N_OUT
#define CDIM   64
#define TOTALC (KVOL*MPAIRS)     // 4,050,000

// Bucketing / sort
#define BROWS  128
#define NBKT   1563              // ceil(200000/128)
#define NSEG   (NBKT*KVOL)       // 42,201 (bkt,k) segments
#define SUBW   10                // sub-chunks per k
#define NWGH   (KVOL*SUBW)       // 270 WGs for hist/scatter
#define CHUNKH (MPAIRS/SUBW)     // 15,000 exact
#define MAXSLOTS 4700000         // >= 4,050,000 + 42,201*15
#define CAPSLOTS 1300000         // per-pass contrib capacity (exp ~1.17M)
#define NPASS  4
#define PASSBKT 391              // ceil(1563/4)

typedef __attribute__((ext_vector_type(8))) short bf16x8;
typedef __attribute__((ext_vector_type(4))) float f32x4;

__device__ __forceinline__ short f2bf(float f) {
  union { float f; uint32_t u; } v; v.f = f;
  uint32_t u = v.u;
  u += 0x7FFF + ((u >> 16) & 1);
  return (short)(u >> 16);
}
__device__ __forceinline__ float bf2f(uint16_t u) {
  union { uint32_t u; float f; } v; v.u = ((uint32_t)u) << 16; return v.f;
}

// ---- prologue converts ----
__global__ void cvt_feats(const float* __restrict__ in, short* __restrict__ out, int n8) {
  int i = blockIdx.x * blockDim.x + threadIdx.x;
  int stride = gridDim.x * blockDim.x;
  for (; i < n8; i += stride) {
    const float* p = in + (size_t)i * 8;
    f32x4 f0 = *(const f32x4*)(p);
    f32x4 f1 = *(const f32x4*)(p + 4);
    bf16x8 o;
    o[0] = f2bf(f0[0]); o[1] = f2bf(f0[1]); o[2] = f2bf(f0[2]); o[3] = f2bf(f0[3]);
    o[4] = f2bf(f1[0]); o[5] = f2bf(f1[1]); o[6] = f2bf(f1[2]); o[7] = f2bf(f1[3]);
    *(bf16x8*)(out + (size_t)i * 8) = o;
  }
}

__global__ void cvt_w(const float* __restrict__ w, short* __restrict__ wt) {
  int k = blockIdx.x;
  const float* wk = w + (size_t)k * CDIM * CDIM;
  short* wtk = wt + (size_t)k * CDIM * CDIM;
  for (int t = threadIdx.x; t < CDIM * CDIM; t += blockDim.x) {
    int j = t >> 6, i = t & 63;
    wtk[j * CDIM + i] = f2bf(wk[i * CDIM + j]);
  }
}

// ---- histogram: WG = (k, sub-chunk); LDS-private 1563 bins ----
__global__ __launch_bounds__(256)
void k_hist(const int* __restrict__ om, unsigned int* __restrict__ hist_g) {
  __shared__ unsigned int h[NBKT];
  const int wg = blockIdx.x, tid = threadIdx.x;
  for (int i = tid; i < NBKT; i += 256) h[i] = 0u;
  __syncthreads();
  const int k = wg / SUBW, sub = wg - k * SUBW;
  const int base = k * MPAIRS + sub * CHUNKH;
  for (int i = tid; i < CHUNKH; i += 256)
    atomicAdd(&h[((unsigned)om[base + i]) >> 7], 1u);
  __syncthreads();
  for (int i = tid; i < NBKT; i += 256)
    hist_g[(size_t)i * NWGH + wg] = h[i];
}

// ---- per-(bkt,k) padded totals ----
__global__ void tp_pad(const unsigned int* __restrict__ hist_g, unsigned int* __restrict__ tp) {
  int idx = blockIdx.x * 256 + threadIdx.x;
  if (idx >= NSEG) return;
  int bkt = idx / KVOL, k = idx - bkt * KVOL;
  const unsigned int* hp = hist_g + (size_t)bkt * NWGH + k * SUBW;
  unsigned int s = 0;
#pragma unroll
  for (int sub = 0; sub < SUBW; ++sub) s += hp[sub];
  tp[idx] = (s + 15u) & ~15u;
}

// ---- 3-kernel exclusive scan over NSEG ----
__global__ void scan_local(const unsigned int* __restrict__ counts,
                           unsigned int* __restrict__ offsets,
                           unsigned int* __restrict__ bsum, int n) {
  __shared__ unsigned int sh[1024];
  int t = threadIdx.x;
  int idx = blockIdx.x * 1024 + t;
  unsigned int v = (idx < n) ? counts[idx] : 0u;
  sh[t] = v; __syncthreads();
  for (int o = 1; o < 1024; o <<= 1) {
    unsigned int u = (t >= o) ? sh[t - o] : 0u;
    __syncthreads();
    sh[t] += u;
    __syncthreads();
  }
  if (idx < n) offsets[idx] = sh[t] - v;
  if (t == 1023) bsum[blockIdx.x] = sh[1023];
}

__global__ void scan_bsum(unsigned int* __restrict__ bsum, int nb) {
  __shared__ unsigned int sh[1024];
  int t = threadIdx.x;
  unsigned int v = (t < nb) ? bsum[t] : 0u;
  sh[t] = v; __syncthreads();
  for (int o = 1; o < 1024; o <<= 1) {
    unsigned int u = (t >= o) ? sh[t - o] : 0u;
    __syncthreads();
    sh[t] += u;
    __syncthreads();
  }
  if (t < nb) bsum[t] = sh[t] - v;
}

__global__ void scan_apply(unsigned int* __restrict__ offsets,
                           const unsigned int* __restrict__ bsum,
                           const unsigned int* __restrict__ counts, int n) {
  int idx = blockIdx.x * 1024 + threadIdx.x;
  if (idx < n) {
    unsigned int o = offsets[idx] + bsum[blockIdx.x];
    offsets[idx] = o;
    if (idx == n - 1) offsets[n] = o + counts[idx];
  }
}

// ---- per-(bkt,k,sub) cursor bases ----
__global__ void base_fill(const unsigned int* __restrict__ hist_g,
                          const unsigned int* __restrict__ offs,
                          unsigned int* __restrict__ base_g) {
  int idx = blockIdx.x * 256 + threadIdx.x;
  if (idx >= NSEG) return;
  int bkt = idx / KVOL, k = idx - bkt * KVOL;
  unsigned int run = offs[idx];
  size_t c = (size_t)bkt * NWGH + k * SUBW;
#pragma unroll
  for (int sub = 0; sub < SUBW; ++sub) {
    base_g[c + sub] = run;
    run += hist_g[c + sub];
  }
}

// ---- scatter packed entries into (bkt,k)-sorted slots; LDS cursors only ----
__global__ __launch_bounds__(256)
void k_scatter(const int* __restrict__ om, const int* __restrict__ im,
               const unsigned int* __restrict__ base_g, unsigned int* __restrict__ sorted_g) {
  __shared__ unsigned int cur[NBKT];
  const int wg = blockIdx.x, tid = threadIdx.x;
  for (int i = tid; i < NBKT; i += 256) cur[i] = base_g[(size_t)i * NWGH + wg];
  __syncthreads();
  const int k = wg / SUBW, sub = wg - k * SUBW;
  const int base = k * MPAIRS + sub * CHUNKH;
  for (int i = tid; i < CHUNKH; i += 256) {
    int e = base + i;
    unsigned int o = (unsigned)om[e];
    unsigned int pos = atomicAdd(&cur[o >> 7], 1u);
    sorted_g[pos] = ((o & 127u) << 23) | ((unsigned)k << 18) | (unsigned)im[e];
  }
}

// ---- GEMM over sorted tiles (same k per tile by construction); coalesced
// contrib writes, zero atomics. Swapped MFMA: lane (r,h) owns entry base+r,
// channels t*16+h*4+{0..3}. ----
__global__ __launch_bounds__(256, 4)
void k_gemm(const short* __restrict__ a_bf16, const short* __restrict__ wt_bf16,
            const unsigned int* __restrict__ sorted_g, const unsigned int* __restrict__ offs,
            short* __restrict__ contrib, int b0, int b1)
{
  const unsigned int s = offs[b0 * KVOL];
  const unsigned int e = offs[b1 * KVOL];
  const int ntiles = (int)((e - s) >> 4);
  const int nw = gridDim.x * 4;
  const int w  = blockIdx.x * 4 + (threadIdx.x >> 6);
  const int chunk = (ntiles + nw - 1) / nw;
  int t0 = w * chunk, t1 = t0 + chunk; if (t1 > ntiles) t1 = ntiles;
  const int lane = threadIdx.x & 63, r = lane & 15, h = lane >> 4;

  int kcur = -1;
  bf16x8 b[4][2];
  for (int t = t0; t < t1; ++t) {
    const unsigned int slot = s + ((unsigned int)t << 4);
    const unsigned int ent = sorted_g[slot + r];
    const int kw = (__shfl((int)ent, 0) >> 18) & 31;   // lane 0 is always real
    if (kw != kcur) {
      kcur = kw;
      const short* wtk = wt_bf16 + (size_t)kw * CDIM * CDIM;
#pragma unroll
      for (int tt = 0; tt < 4; ++tt)
#pragma unroll
        for (int c = 0; c < 2; ++c)
          b[tt][c] = *(const bf16x8*)(wtk + (tt * 16 + r) * CDIM + c * 32 + h * 8);
    }
    const unsigned int inrow = ent & 0x3FFFFu;         // dummies decode to a valid row
    const short* arow = a_bf16 + (size_t)inrow * CDIM;
    bf16x8 a0 = *(const bf16x8*)(arow + h * 8);
    bf16x8 a1 = *(const bf16x8*)(arow + 32 + h * 8);

    f32x4 acc[4];
#pragma unroll
    for (int tt = 0; tt < 4; ++tt) {
      acc[tt] = (f32x4){0.f, 0.f, 0.f, 0.f};
      acc[tt] = __builtin_amdgcn_mfma_f32_16x16x32_bf16(b[tt][0], a0, acc[tt], 0, 0, 0);
      acc[tt] = __builtin_amdgcn_mfma_f32_16x16x32_bf16(b[tt][1], a1, acc[tt], 0, 0, 0);
    }

    const unsigned int ci = slot + r - s;              // pass-local slot
    if (slot - s + 16u <= (unsigned)CAPSLOTS) {        // wave-uniform guard
      short* crow = contrib + (size_t)ci * CDIM;
#pragma unroll
      for (int tt = 0; tt < 4; ++tt) {
        short4 s4;
        s4.x = f2bf(acc[tt][0]); s4.y = f2bf(acc[tt][1]);
        s4.z = f2bf(acc[tt][2]); s4.w = f2bf(acc[tt][3]);
        *(short4*)(crow + tt * 16 + h * 4) = s4;
      }
    }
  }
}

// ---- reduce: one WG per bucket; stream contiguous slots; lane = channel;
// one ds_add_f32 per entry; coalesced f32 writeout (covers d_out fully) ----
__global__ __launch_bounds__(256, 4)
void k_reduce(const short* __restrict__ contrib,
              const unsigned int* __restrict__ sorted_g,
              const unsigned int* __restrict__ offs,
              float* __restrict__ out, int b0)
{
  __shared__ float accum[BROWS * 65];
  const int bkt = b0 + blockIdx.x;
  const int tid = threadIdx.x, lane = tid & 63, wv = tid >> 6;
  for (int i = tid; i < BROWS * 65; i += 256) accum[i] = 0.f;
  __syncthreads();

  const unsigned int pbase = offs[b0 * KVOL];
  const unsigned int s = offs[bkt * KVOL];
  const unsigned int e = offs[(bkt + 1) * KVOL];
  const uint16_t* cb = (const uint16_t*)contrib;

  for (unsigned int j = s + wv; j < e; j += 4) {
    const unsigned int ent = sorted_g[j];              // wave-uniform
    const unsigned int outl = (ent >> 23) & 0xFFu;
    const float v = bf2f(cb[(size_t)(j - pbase) * CDIM + lane]);
    if (outl < 128u)                                   // skip pad dummies
      atomicAdd(&accum[outl * 65 + lane], v);
  }
  __syncthreads();

  const int rowbase = bkt * BROWS;
  int valid = NROWS - rowbase; if (valid > BROWS) valid = BROWS;
  for (int sI = tid; sI < valid * 16; sI += 256) {
    int row = sI >> 4, c4 = sI & 15;
    const float* ap = &accum[row * 65 + c4 * 4];
    float4 v; v.x = ap[0]; v.y = ap[1]; v.z = ap[2]; v.w = ap[3];
    *(float4*)(out + ((size_t)(rowbase + row)) * CDIM + c4 * 4) = v;
  }
}

extern "C" void kernel_launch(void* const* d_in, const int* in_sizes, int n_in,
                              void* d_out, int out_size, void* d_ws, size_t ws_size,
                              hipStream_t stream) {
  const float* in_feats = (const float*)d_in[0];
  const float* kernel   = (const float*)d_in[1];
  const int*   in_map   = (const int*)d_in[2];
  const int*   out_map  = (const int*)d_in[3];
  float* out = (float*)d_out;

  uint8_t* ws = (uint8_t*)d_ws;
  size_t off = 0;
  auto alloc = [&](size_t bytes) -> void* {
    void* p = ws + off;
    off += (bytes + 255) & ~(size_t)255;
    return p;
  };
  short* in_bf16       = (short*)alloc((size_t)NROWS * CDIM * 2);          // 25.6 MB
  short* wt_bf16       = (short*)alloc((size_t)KVOL * CDIM * CDIM * 2);    // 221 KB
  unsigned int* hist_g = (unsigned int*)alloc((size_t)NBKT * NWGH * 4);    // 1.69 MB
  unsigned int* base_g = (unsigned int*)alloc((size_t)NBKT * NWGH * 4);    // 1.69 MB
  unsigned int* tp     = (unsigned int*)alloc((size_t)(NSEG + 1) * 4);     // 169 KB
  unsigned int* offs   = (unsigned int*)alloc((size_t)(NSEG + 1) * 4);     // 169 KB
  unsigned int* bsum   = (unsigned int*)alloc(4096);
  unsigned int* sorted_g = (unsigned int*)alloc((size_t)MAXSLOTS * 4);     // 18.8 MB
  short* contrib       = (short*)alloc((size_t)CAPSLOTS * CDIM * 2);       // 166.4 MB

  // dummies: 0x40404040 -> outl=128 (skip flag), inrow=16448 (valid row)
  hipMemsetAsync(sorted_g, 0x40, (size_t)MAXSLOTS * 4, stream);

  cvt_feats<<<2048, 256, 0, stream>>>(in_feats, in_bf16, NROWS * CDIM / 8);
  cvt_w<<<KVOL, 256, 0, stream>>>(kernel, wt_bf16);

  k_hist<<<NWGH, 256, 0, stream>>>(out_map, hist_g);
  tp_pad<<<(NSEG + 255) / 256, 256, 0, stream>>>(hist_g, tp);

  const int sb = (NSEG + 1023) / 1024;   // 42
  scan_local<<<sb, 1024, 0, stream>>>(tp, offs, bsum, NSEG);
  scan_bsum<<<1, 1024, 0, stream>>>(bsum, sb);
  scan_apply<<<sb, 1024, 0, stream>>>(offs, bsum, tp, NSEG);
  base_fill<<<(NSEG + 255) / 256, 256, 0, stream>>>(hist_g, offs, base_g);

  k_scatter<<<NWGH, 256, 0, stream>>>(out_map, in_map, base_g, sorted_g);

  for (int p = 0; p < NPASS; ++p) {
    int b0 = p * PASSBKT;
    int b1 = b0 + PASSBKT; if (b1 > NBKT) b1 = NBKT;
    k_gemm<<<1024, 256, 0, stream>>>(in_bf16, wt_bf16, sorted_g, offs, contrib, b0, b1);
    k_reduce<<<b1 - b0, 256, 0, stream>>>(contrib, sorted_g, offs, out, b0);
  }
}

// Round 10
// 641.208 us; speedup vs baseline: 3.4328x; 3.4328x over previous
//
#include <hip/hip_runtime.h>
#include <hip/hip_bf16.h>
#include <stdint.h>

// Problem constants
#define KVOL   27
#define MPAIRS 150000
#define NROWS  200000            // N_IN == N_OUT
#define CDIM   64
#define TOTALC (KVOL*MPAIRS)     // 4,050,000

// Pass / bucket geometry
#define NPASS  3
#define KPP    9                 // k-offsets per pass
#define PASSC  (KPP*MPAIRS)      // 1,350,000 (21 bits)
#define BROWS  128
#define NBKT   1563              // ceil(200000/128)
#define NPB    (NPASS*NBKT)      // 4689 (pass,bucket) bins
#define SUBW   5                 // sub-chunks per k for hist/scatter
#define NWGH   (KVOL*SUBW)       // 135 WGs
#define CHUNKH (MPAIRS/SUBW)     // 30,000 exact
#define CELLS  (NPB*NWGH)        // 633,015 scan cells
#define ECAP   1280              // per-(pass,bucket) entry capacity (mean 864, sd 29)

typedef __attribute__((ext_vector_type(8))) short bf16x8;
typedef __attribute__((ext_vector_type(4))) float f32x4;

__device__ __forceinline__ short f2bf(float f) {
  union { float f; uint32_t u; } v; v.f = f;
  uint32_t u = v.u;
  u += 0x7FFF + ((u >> 16) & 1);
  return (short)(u >> 16);
}
__device__ __forceinline__ float bf2f(uint16_t u) {
  union { uint32_t u; float f; } v; v.u = ((uint32_t)u) << 16; return v.f;
}

// ---- prologue converts ----
__global__ void cvt_feats(const float* __restrict__ in, short* __restrict__ out, int n8) {
  int i = blockIdx.x * blockDim.x + threadIdx.x;
  int stride = gridDim.x * blockDim.x;
  for (; i < n8; i += stride) {
    const float* p = in + (size_t)i * 8;
    f32x4 f0 = *(const f32x4*)(p);
    f32x4 f1 = *(const f32x4*)(p + 4);
    bf16x8 o;
    o[0] = f2bf(f0[0]); o[1] = f2bf(f0[1]); o[2] = f2bf(f0[2]); o[3] = f2bf(f0[3]);
    o[4] = f2bf(f1[0]); o[5] = f2bf(f1[1]); o[6] = f2bf(f1[2]); o[7] = f2bf(f1[3]);
    *(bf16x8*)(out + (size_t)i * 8) = o;
  }
}

__global__ void cvt_w(const float* __restrict__ w, short* __restrict__ wt) {
  int k = blockIdx.x;
  const float* wk = w + (size_t)k * CDIM * CDIM;
  short* wtk = wt + (size_t)k * CDIM * CDIM;
  for (int t = threadIdx.x; t < CDIM * CDIM; t += blockDim.x) {
    int j = t >> 6, i = t & 63;
    wtk[j * CDIM + i] = f2bf(wk[i * CDIM + j]);
  }
}

// ---- histogram: WG = (k, sub-chunk); LDS-private 1563 bucket bins ----
__global__ __launch_bounds__(256)
void k_hist(const int* __restrict__ om, unsigned int* __restrict__ hist_g) {
  __shared__ unsigned int h[NBKT];
  const int wg = blockIdx.x, tid = threadIdx.x;
  const int k = wg / SUBW, sub = wg - k * SUBW;
  const int pass = k / KPP;
  for (int i = tid; i < NBKT; i += 256) h[i] = 0u;
  __syncthreads();
  const int base = k * MPAIRS + sub * CHUNKH;
  for (int i = tid; i < CHUNKH; i += 256)
    atomicAdd(&h[((unsigned)om[base + i]) >> 7], 1u);
  __syncthreads();
  for (int b = tid; b < NBKT; b += 256)
    hist_g[(size_t)(pass * NBKT + b) * NWGH + wg] = h[b];
}

// ---- 3-kernel exclusive scan over CELLS ([bin][wg] cell-major) ----
__global__ void scan_local(const unsigned int* __restrict__ counts,
                           unsigned int* __restrict__ offsets,
                           unsigned int* __restrict__ bsum, int n) {
  __shared__ unsigned int sh[1024];
  int t = threadIdx.x;
  int idx = blockIdx.x * 1024 + t;
  unsigned int v = (idx < n) ? counts[idx] : 0u;
  sh[t] = v; __syncthreads();
  for (int o = 1; o < 1024; o <<= 1) {
    unsigned int u = (t >= o) ? sh[t - o] : 0u;
    __syncthreads();
    sh[t] += u;
    __syncthreads();
  }
  if (idx < n) offsets[idx] = sh[t] - v;
  if (t == 1023) bsum[blockIdx.x] = sh[1023];
}

__global__ void scan_bsum(unsigned int* __restrict__ bsum, int nb) {
  __shared__ unsigned int sh[1024];
  int t = threadIdx.x;
  unsigned int v = (t < nb) ? bsum[t] : 0u;
  sh[t] = v; __syncthreads();
  for (int o = 1; o < 1024; o <<= 1) {
    unsigned int u = (t >= o) ? sh[t - o] : 0u;
    __syncthreads();
    sh[t] += u;
    __syncthreads();
  }
  if (t < nb) bsum[t] = sh[t] - v;
}

__global__ void scan_apply(unsigned int* __restrict__ offsets,
                           const unsigned int* __restrict__ bsum,
                           const unsigned int* __restrict__ counts, int n) {
  int idx = blockIdx.x * 1024 + threadIdx.x;
  if (idx < n) {
    unsigned int o = offsets[idx] + bsum[blockIdx.x];
    offsets[idx] = o;
    if (idx == n - 1) offsets[n] = o + counts[idx];
  }
}

// ---- scatter 4B entries (outl<<21 | e_local) into (pass,bucket) slots ----
__global__ __launch_bounds__(256)
void k_scatter(const int* __restrict__ om,
               const unsigned int* __restrict__ offs, unsigned int* __restrict__ sorted_g) {
  __shared__ unsigned int cur[NBKT];
  const int wg = blockIdx.x, tid = threadIdx.x;
  const int k = wg / SUBW, sub = wg - k * SUBW;
  const int pass = k / KPP, kk = k - pass * KPP;
  for (int b = tid; b < NBKT; b += 256)
    cur[b] = offs[(size_t)(pass * NBKT + b) * NWGH + wg];
  __syncthreads();
  const int base = k * MPAIRS + sub * CHUNKH;
  const unsigned int elb = (unsigned)(kk * MPAIRS + sub * CHUNKH);
  for (int i = tid; i < CHUNKH; i += 256) {
    unsigned int o = (unsigned)om[base + i];
    unsigned int pos = atomicAdd(&cur[o >> 7], 1u);
    sorted_g[pos] = ((o & 127u) << 21) | (elb + (unsigned)i);
  }
}

// ---- GEMM (per pass): ORIGINAL k-major order, coalesced contrib writes,
// zero atomics, zero indirection. Swapped MFMA: lane (r,h) owns pair base+r,
// channels t*16+h*4+{0..3}. ----
__global__ __launch_bounds__(256, 4)
void k_gemm(const short* __restrict__ a_bf16, const short* __restrict__ wt_bf16,
            const int* __restrict__ in_map, short* __restrict__ contrib, int pass)
{
  const int kk   = blockIdx.y;
  const int k    = pass * KPP + kk;
  const int lane = threadIdx.x & 63;
  const int wave = threadIdx.x >> 6;
  const int r    = lane & 15;
  const int h    = lane >> 4;

  bf16x8 b[4][2];
  const short* wtk = wt_bf16 + (size_t)k * CDIM * CDIM;
#pragma unroll
  for (int t = 0; t < 4; ++t)
#pragma unroll
    for (int c = 0; c < 2; ++c)
      b[t][c] = *(const bf16x8*)(wtk + (t * 16 + r) * CDIM + c * 32 + h * 8);

  const int* imk = in_map + (size_t)k * MPAIRS;
  const int ntiles = MPAIRS / 16;
  const int wstride = gridDim.x * 4;

  for (int tile = blockIdx.x * 4 + wave; tile < ntiles; tile += wstride) {
    const int base = tile * 16;
    const int in_row = imk[base + r];
    const short* arow = a_bf16 + (size_t)in_row * CDIM;
    bf16x8 a0 = *(const bf16x8*)(arow + h * 8);
    bf16x8 a1 = *(const bf16x8*)(arow + 32 + h * 8);

    f32x4 acc[4];
#pragma unroll
    for (int t = 0; t < 4; ++t) {
      acc[t] = (f32x4){0.f, 0.f, 0.f, 0.f};
      acc[t] = __builtin_amdgcn_mfma_f32_16x16x32_bf16(b[t][0], a0, acc[t], 0, 0, 0);
      acc[t] = __builtin_amdgcn_mfma_f32_16x16x32_bf16(b[t][1], a1, acc[t], 0, 0, 0);
    }

    short* crow = contrib + (size_t)(kk * MPAIRS + base + r) * CDIM;
#pragma unroll
    for (int t = 0; t < 4; ++t) {
      short4 s4;
      s4.x = f2bf(acc[t][0]); s4.y = f2bf(acc[t][1]);
      s4.z = f2bf(acc[t][2]); s4.w = f2bf(acc[t][3]);
      *(short4*)(crow + t * 16 + h * 4) = s4;
    }
  }
}

// ---- reduce (per pass): WG per bucket; in-LDS row-sort of ~864 entries;
// then one wave per row batch: 4 waves x 32 rows = all 128 bucket rows,
// register accumulation (no atomics on data). ----
__global__ __launch_bounds__(256, 8)
void k_reduce(const short* __restrict__ contrib,
              const unsigned int* __restrict__ sorted_g,
              const unsigned int* __restrict__ offs,
              float* __restrict__ out, int pass)
{
  __shared__ unsigned int ents[ECAP];
  __shared__ unsigned int h[BROWS], bs[BROWS], cur[BROWS];

  const int bkt = blockIdx.x, tid = threadIdx.x;
  const int bin = pass * NBKT + bkt;
  const unsigned int s = offs[(size_t)bin * NWGH];
  const unsigned int e = offs[(size_t)(bin + 1) * NWGH];
  int cnt = (int)(e - s); if (cnt > ECAP) cnt = ECAP;   // astronomically unlikely clamp

  if (tid < BROWS) h[tid] = 0u;
  __syncthreads();
  for (int i = tid; i < cnt; i += 256)
    atomicAdd(&h[sorted_g[s + i] >> 21], 1u);
  __syncthreads();
  if (tid == 0) {
    unsigned int run = 0;
    for (int r = 0; r < BROWS; ++r) { bs[r] = run; run += h[r]; }
  }
  __syncthreads();
  if (tid < BROWS) cur[tid] = bs[tid];
  __syncthreads();
  for (int i = tid; i < cnt; i += 256) {
    unsigned int en = sorted_g[s + i];
    unsigned int pos = atomicAdd(&cur[en >> 21], 1u);
    ents[pos] = en;
  }
  __syncthreads();

  const int lane = tid & 63, wv = tid >> 6;
  const uint16_t* cb = (const uint16_t*)contrib;
#pragma unroll 1
  for (int rr = 0; rr < 32; ++rr) {                   // 4 waves x 32 rows = 128
    const int row = wv * 32 + rr;
    const int grow = bkt * BROWS + row;
    if (grow >= NROWS) break;
    float acc = (pass == 0) ? 0.f : out[(size_t)grow * CDIM + lane];
    float acc2 = 0.f;
    int j = (int)bs[row];
    const int je = j + (int)h[row];
    for (; j + 1 < je; j += 2) {                      // 2-way MLP unroll
      unsigned int el0 = ents[j] & 0x1FFFFFu;
      unsigned int el1 = ents[j + 1] & 0x1FFFFFu;
      acc  += bf2f(cb[(size_t)el0 * CDIM + lane]);
      acc2 += bf2f(cb[(size_t)el1 * CDIM + lane]);
    }
    if (j < je) acc += bf2f(cb[(size_t)(ents[j] & 0x1FFFFFu) * CDIM + lane]);
    out[(size_t)grow * CDIM + lane] = acc + acc2;
  }
}

extern "C" void kernel_launch(void* const* d_in, const int* in_sizes, int n_in,
                              void* d_out, int out_size, void* d_ws, size_t ws_size,
                              hipStream_t stream) {
  const float* in_feats = (const float*)d_in[0];
  const float* kernel   = (const float*)d_in[1];
  const int*   in_map   = (const int*)d_in[2];
  const int*   out_map  = (const int*)d_in[3];
  float* out = (float*)d_out;

  uint8_t* ws = (uint8_t*)d_ws;
  size_t off = 0;
  auto alloc = [&](size_t bytes) -> void* {
    void* p = ws + off;
    off += (bytes + 255) & ~(size_t)255;
    return p;
  };
  short* in_bf16         = (short*)alloc((size_t)NROWS * CDIM * 2);        // 25.6 MB
  short* wt_bf16         = (short*)alloc((size_t)KVOL * CDIM * CDIM * 2);  // 221 KB
  unsigned int* hist_g   = (unsigned int*)alloc((size_t)CELLS * 4);        // 2.53 MB
  unsigned int* offs     = (unsigned int*)alloc((size_t)(CELLS + 1) * 4);  // 2.53 MB
  unsigned int* bsum     = (unsigned int*)alloc(4096);
  unsigned int* sorted_g = (unsigned int*)alloc((size_t)TOTALC * 4);       // 16.2 MB
  short* contrib         = (short*)alloc((size_t)PASSC * CDIM * 2);        // 172.8 MB

  hipMemsetAsync(hist_g, 0, (size_t)CELLS * 4, stream);

  cvt_feats<<<2048, 256, 0, stream>>>(in_feats, in_bf16, NROWS * CDIM / 8);
  cvt_w<<<KVOL, 256, 0, stream>>>(kernel, wt_bf16);

  k_hist<<<NWGH, 256, 0, stream>>>(out_map, hist_g);

  const int sb = (CELLS + 1023) / 1024;   // 619
  scan_local<<<sb, 1024, 0, stream>>>(hist_g, offs, bsum, CELLS);
  scan_bsum<<<1, 1024, 0, stream>>>(bsum, sb);
  scan_apply<<<sb, 1024, 0, stream>>>(offs, bsum, hist_g, CELLS);

  k_scatter<<<NWGH, 256, 0, stream>>>(out_map, offs, sorted_g);

  for (int p = 0; p < NPASS; ++p) {
    dim3 g(128, KPP);
    k_gemm<<<g, 256, 0, stream>>>(in_bf16, wt_bf16, in_map, contrib, p);
    k_reduce<<<NBKT, 256, 0, stream>>>(contrib, sorted_g, offs, out, p);
  }
}

// Round 11
// 618.823 us; speedup vs baseline: 3.5570x; 1.0362x over previous
//
#include <hip/hip_runtime.h>
#include <hip/hip_bf16.h>
#include <stdint.h>

// Problem constants
#define KVOL   27
#define MPAIRS 150000
#define NROWS  200000            // N_IN == N_OUT
#define CDIM   64
#define TOTALC (KVOL*MPAIRS)     // 4,050,000

// Pass / bucket geometry
#define NPASS  3
#define KPP    9                 // k-offsets per pass
#define PASSC  (KPP*MPAIRS)      // 1,350,000 (21 bits)
#define BROWS  128
#define NBKT   1563              // ceil(200000/128)
#define NPB    (NPASS*NBKT)      // 4689 (pass,bucket) bins
#define SUBW   5                 // sub-chunks per k for hist/scatter
#define NWGH   (KVOL*SUBW)       // 135 WGs
#define CHUNKH (MPAIRS/SUBW)     // 30,000 exact
#define CELLS  (NPB*NWGH)        // 633,015 scan cells
#define ECAP   1280              // per-(pass,bucket) entry capacity (mean 864, sd 29)

typedef __attribute__((ext_vector_type(8))) short bf16x8;
typedef __attribute__((ext_vector_type(4))) float f32x4;

__device__ __forceinline__ short f2bf(float f) {
  union { float f; uint32_t u; } v; v.f = f;
  uint32_t u = v.u;
  u += 0x7FFF + ((u >> 16) & 1);
  return (short)(u >> 16);
}
__device__ __forceinline__ float bf2f(uint16_t u) {
  union { uint32_t u; float f; } v; v.u = ((uint32_t)u) << 16; return v.f;
}

// ---- prologue converts ----
__global__ void cvt_feats(const float* __restrict__ in, short* __restrict__ out, int n8) {
  int i = blockIdx.x * blockDim.x + threadIdx.x;
  int stride = gridDim.x * blockDim.x;
  for (; i < n8; i += stride) {
    const float* p = in + (size_t)i * 8;
    f32x4 f0 = *(const f32x4*)(p);
    f32x4 f1 = *(const f32x4*)(p + 4);
    bf16x8 o;
    o[0] = f2bf(f0[0]); o[1] = f2bf(f0[1]); o[2] = f2bf(f0[2]); o[3] = f2bf(f0[3]);
    o[4] = f2bf(f1[0]); o[5] = f2bf(f1[1]); o[6] = f2bf(f1[2]); o[7] = f2bf(f1[3]);
    *(bf16x8*)(out + (size_t)i * 8) = o;
  }
}

__global__ void cvt_w(const float* __restrict__ w, short* __restrict__ wt) {
  int k = blockIdx.x;
  const float* wk = w + (size_t)k * CDIM * CDIM;
  short* wtk = wt + (size_t)k * CDIM * CDIM;
  for (int t = threadIdx.x; t < CDIM * CDIM; t += blockDim.x) {
    int j = t >> 6, i = t & 63;
    wtk[j * CDIM + i] = f2bf(wk[i * CDIM + j]);
  }
}

// ---- histogram: WG = (k, sub-chunk); LDS-private 1563 bucket bins ----
__global__ __launch_bounds__(256)
void k_hist(const int* __restrict__ om, unsigned int* __restrict__ hist_g) {
  __shared__ unsigned int h[NBKT];
  const int wg = blockIdx.x, tid = threadIdx.x;
  const int k = wg / SUBW, sub = wg - k * SUBW;
  const int pass = k / KPP;
  for (int i = tid; i < NBKT; i += 256) h[i] = 0u;
  __syncthreads();
  const int base = k * MPAIRS + sub * CHUNKH;
  for (int i = tid; i < CHUNKH; i += 256)
    atomicAdd(&h[((unsigned)om[base + i]) >> 7], 1u);
  __syncthreads();
  for (int b = tid; b < NBKT; b += 256)
    hist_g[(size_t)(pass * NBKT + b) * NWGH + wg] = h[b];
}

// ---- 3-kernel exclusive scan over CELLS ([bin][wg] cell-major) ----
__global__ void scan_local(const unsigned int* __restrict__ counts,
                           unsigned int* __restrict__ offsets,
                           unsigned int* __restrict__ bsum, int n) {
  __shared__ unsigned int sh[1024];
  int t = threadIdx.x;
  int idx = blockIdx.x * 1024 + t;
  unsigned int v = (idx < n) ? counts[idx] : 0u;
  sh[t] = v; __syncthreads();
  for (int o = 1; o < 1024; o <<= 1) {
    unsigned int u = (t >= o) ? sh[t - o] : 0u;
    __syncthreads();
    sh[t] += u;
    __syncthreads();
  }
  if (idx < n) offsets[idx] = sh[t] - v;
  if (t == 1023) bsum[blockIdx.x] = sh[1023];
}

__global__ void scan_bsum(unsigned int* __restrict__ bsum, int nb) {
  __shared__ unsigned int sh[1024];
  int t = threadIdx.x;
  unsigned int v = (t < nb) ? bsum[t] : 0u;
  sh[t] = v; __syncthreads();
  for (int o = 1; o < 1024; o <<= 1) {
    unsigned int u = (t >= o) ? sh[t - o] : 0u;
    __syncthreads();
    sh[t] += u;
    __syncthreads();
  }
  if (t < nb) bsum[t] = sh[t] - v;
}

__global__ void scan_apply(unsigned int* __restrict__ offsets,
                           const unsigned int* __restrict__ bsum,
                           const unsigned int* __restrict__ counts, int n) {
  int idx = blockIdx.x * 1024 + threadIdx.x;
  if (idx < n) {
    unsigned int o = offsets[idx] + bsum[blockIdx.x];
    offsets[idx] = o;
    if (idx == n - 1) offsets[n] = o + counts[idx];
  }
}

// ---- scatter 4B entries (outl<<21 | e_local) into (pass,bucket) slots ----
__global__ __launch_bounds__(256)
void k_scatter(const int* __restrict__ om,
               const unsigned int* __restrict__ offs, unsigned int* __restrict__ sorted_g) {
  __shared__ unsigned int cur[NBKT];
  const int wg = blockIdx.x, tid = threadIdx.x;
  const int k = wg / SUBW, sub = wg - k * SUBW;
  const int pass = k / KPP, kk = k - pass * KPP;
  for (int b = tid; b < NBKT; b += 256)
    cur[b] = offs[(size_t)(pass * NBKT + b) * NWGH + wg];
  __syncthreads();
  const int base = k * MPAIRS + sub * CHUNKH;
  const unsigned int elb = (unsigned)(kk * MPAIRS + sub * CHUNKH);
  for (int i = tid; i < CHUNKH; i += 256) {
    unsigned int o = (unsigned)om[base + i];
    unsigned int pos = atomicAdd(&cur[o >> 7], 1u);
    sorted_g[pos] = ((o & 127u) << 21) | (elb + (unsigned)i);
  }
}

// ---- GEMM (per pass): ORIGINAL k-major order, coalesced contrib writes,
// zero atomics, zero indirection. Swapped MFMA: lane (r,h) owns pair base+r,
// channels t*16+h*4+{0..3}. 8 blocks/CU (VGPR=32) for gather MLP. ----
__global__ __launch_bounds__(256, 8)
void k_gemm(const short* __restrict__ a_bf16, const short* __restrict__ wt_bf16,
            const int* __restrict__ in_map, short* __restrict__ contrib, int pass)
{
  const int kk   = blockIdx.y;
  const int k    = pass * KPP + kk;
  const int lane = threadIdx.x & 63;
  const int wave = threadIdx.x >> 6;
  const int r    = lane & 15;
  const int h    = lane >> 4;

  bf16x8 b[4][2];
  const short* wtk = wt_bf16 + (size_t)k * CDIM * CDIM;
#pragma unroll
  for (int t = 0; t < 4; ++t)
#pragma unroll
    for (int c = 0; c < 2; ++c)
      b[t][c] = *(const bf16x8*)(wtk + (t * 16 + r) * CDIM + c * 32 + h * 8);

  const int* imk = in_map + (size_t)k * MPAIRS;
  const int ntiles = MPAIRS / 16;
  const int wstride = gridDim.x * 4;

  for (int tile = blockIdx.x * 4 + wave; tile < ntiles; tile += wstride) {
    const int base = tile * 16;
    const int in_row = imk[base + r];
    const short* arow = a_bf16 + (size_t)in_row * CDIM;
    bf16x8 a0 = *(const bf16x8*)(arow + h * 8);
    bf16x8 a1 = *(const bf16x8*)(arow + 32 + h * 8);

    f32x4 acc[4];
#pragma unroll
    for (int t = 0; t < 4; ++t) {
      acc[t] = (f32x4){0.f, 0.f, 0.f, 0.f};
      acc[t] = __builtin_amdgcn_mfma_f32_16x16x32_bf16(b[t][0], a0, acc[t], 0, 0, 0);
      acc[t] = __builtin_amdgcn_mfma_f32_16x16x32_bf16(b[t][1], a1, acc[t], 0, 0, 0);
    }

    short* crow = contrib + (size_t)(kk * MPAIRS + base + r) * CDIM;
#pragma unroll
    for (int t = 0; t < 4; ++t) {
      short4 s4;
      s4.x = f2bf(acc[t][0]); s4.y = f2bf(acc[t][1]);
      s4.z = f2bf(acc[t][2]); s4.w = f2bf(acc[t][3]);
      *(short4*)(crow + t * 16 + h * 4) = s4;
    }
  }
}

// ---- reduce (per pass): WG(512 thr, 8 waves) per bucket; in-LDS row-sort;
// each wave owns 16 rows -> shorter serial gather chains; register accum. ----
__global__ __launch_bounds__(512, 8)
void k_reduce(const short* __restrict__ contrib,
              const unsigned int* __restrict__ sorted_g,
              const unsigned int* __restrict__ offs,
              float* __restrict__ out, int pass)
{
  __shared__ unsigned int ents[ECAP];
  __shared__ unsigned int h[BROWS], bs[BROWS], cur[BROWS];

  const int bkt = blockIdx.x, tid = threadIdx.x;
  const int bin = pass * NBKT + bkt;
  const unsigned int s = offs[(size_t)bin * NWGH];
  const unsigned int e = offs[(size_t)(bin + 1) * NWGH];
  int cnt = (int)(e - s); if (cnt > ECAP) cnt = ECAP;   // astronomically unlikely clamp

  if (tid < BROWS) h[tid] = 0u;
  __syncthreads();
  for (int i = tid; i < cnt; i += 512)
    atomicAdd(&h[sorted_g[s + i] >> 21], 1u);
  __syncthreads();
  if (tid == 0) {
    unsigned int run = 0;
    for (int r = 0; r < BROWS; ++r) { bs[r] = run; run += h[r]; }
  }
  __syncthreads();
  if (tid < BROWS) cur[tid] = bs[tid];
  __syncthreads();
  for (int i = tid; i < cnt; i += 512) {
    unsigned int en = sorted_g[s + i];
    unsigned int pos = atomicAdd(&cur[en >> 21], 1u);
    ents[pos] = en;
  }
  __syncthreads();

  const int lane = tid & 63, wv = tid >> 6;            // 8 waves
  const uint16_t* cb = (const uint16_t*)contrib;
#pragma unroll 1
  for (int rr = 0; rr < 16; ++rr) {                    // 8 waves x 16 rows = 128
    const int row = wv * 16 + rr;
    const int grow = bkt * BROWS + row;
    if (grow >= NROWS) break;
    if (h[row] == 0u && pass) continue;                // untouched row: skip RW
    float acc = (pass == 0) ? 0.f : out[(size_t)grow * CDIM + lane];
    float acc2 = 0.f;
    int j = (int)bs[row];
    const int je = j + (int)h[row];
    for (; j + 1 < je; j += 2) {                       // 2-way MLP unroll
      unsigned int el0 = ents[j] & 0x1FFFFFu;
      unsigned int el1 = ents[j + 1] & 0x1FFFFFu;
      acc  += bf2f(cb[(size_t)el0 * CDIM + lane]);
      acc2 += bf2f(cb[(size_t)el1 * CDIM + lane]);
    }
    if (j < je) acc += bf2f(cb[(size_t)(ents[j] & 0x1FFFFFu) * CDIM + lane]);
    out[(size_t)grow * CDIM + lane] = acc + acc2;
  }
}

extern "C" void kernel_launch(void* const* d_in, const int* in_sizes, int n_in,
                              void* d_out, int out_size, void* d_ws, size_t ws_size,
                              hipStream_t stream) {
  const float* in_feats = (const float*)d_in[0];
  const float* kernel   = (const float*)d_in[1];
  const int*   in_map   = (const int*)d_in[2];
  const int*   out_map  = (const int*)d_in[3];
  float* out = (float*)d_out;

  uint8_t* ws = (uint8_t*)d_ws;
  size_t off = 0;
  auto alloc = [&](size_t bytes) -> void* {
    void* p = ws + off;
    off += (bytes + 255) & ~(size_t)255;
    return p;
  };
  short* in_bf16         = (short*)alloc((size_t)NROWS * CDIM * 2);        // 25.6 MB
  short* wt_bf16         = (short*)alloc((size_t)KVOL * CDIM * CDIM * 2);  // 221 KB
  unsigned int* hist_g   = (unsigned int*)alloc((size_t)CELLS * 4);        // 2.53 MB
  unsigned int* offs     = (unsigned int*)alloc((size_t)(CELLS + 1) * 4);  // 2.53 MB
  unsigned int* bsum     = (unsigned int*)alloc(4096);
  unsigned int* sorted_g = (unsigned int*)alloc((size_t)TOTALC * 4);       // 16.2 MB
  short* contrib         = (short*)alloc((size_t)PASSC * CDIM * 2);        // 172.8 MB

  hipMemsetAsync(hist_g, 0, (size_t)CELLS * 4, stream);

  cvt_feats<<<2048, 256, 0, stream>>>(in_feats, in_bf16, NROWS * CDIM / 8);
  cvt_w<<<KVOL, 256, 0, stream>>>(kernel, wt_bf16);

  k_hist<<<NWGH, 256, 0, stream>>>(out_map, hist_g);

  const int sb = (CELLS + 1023) / 1024;   // 619
  scan_local<<<sb, 1024, 0, stream>>>(hist_g, offs, bsum, CELLS);
  scan_bsum<<<1, 1024, 0, stream>>>(bsum, sb);
  scan_apply<<<sb, 1024, 0, stream>>>(offs, bsum, hist_g, CELLS);

  k_scatter<<<NWGH, 256, 0, stream>>>(out_map, offs, sorted_g);

  for (int p = 0; p < NPASS; ++p) {
    dim3 g(227, KPP);   // 2043 blocks ~= 8/CU capacity, no straggler tail
    k_gemm<<<g, 256, 0, stream>>>(in_bf16, wt_bf16, in_map, contrib, p);
    k_reduce<<<NBKT, 512, 0, stream>>>(contrib, sorted_g, offs, out, p);
  }
}

// Round 12
// 571.129 us; speedup vs baseline: 3.8540x; 1.0835x over previous
//
#include <hip/hip_runtime.h>
#include <hip/hip_bf16.h>
#include <stdint.h>

// Problem constants
#define KVOL   27
#define MPAIRS 150000
#define NROWS  200000            // N_IN == N_OUT
#define CDIM   64
#define TOTALC (KVOL*MPAIRS)     // 4,050,000

// Pass / bucket geometry
#define NPASS  3
#define KPP    9                 // k-offsets per pass
#define PASSC  (KPP*MPAIRS)      // 1,350,000 (21 bits)
#define BROWS  128
#define NBKT   1563              // ceil(200000/128)
#define NPB    (NPASS*NBKT)      // 4689 (pass,bucket) bins
#define SUBW   5                 // sub-chunks per k for hist/scatter
#define NWGH   (KVOL*SUBW)       // 135 WGs
#define CHUNKH (MPAIRS/SUBW)     // 30,000 exact
#define CELLS  (NPB*NWGH)        // 633,015 scan cells
#define ECAP   1280              // per-(pass,bucket) entry capacity (mean 864, sd 29)

typedef __attribute__((ext_vector_type(8))) short bf16x8;
typedef __attribute__((ext_vector_type(4))) float f32x4;

__device__ __forceinline__ short f2bf(float f) {
  union { float f; uint32_t u; } v; v.f = f;
  uint32_t u = v.u;
  u += 0x7FFF + ((u >> 16) & 1);
  return (short)(u >> 16);
}
__device__ __forceinline__ float bf2f(uint32_t u16) {
  union { uint32_t u; float f; } v; v.u = u16 << 16; return v.f;
}

// ---- prologue converts ----
__global__ void cvt_feats(const float* __restrict__ in, short* __restrict__ out, int n8) {
  int i = blockIdx.x * blockDim.x + threadIdx.x;
  int stride = gridDim.x * blockDim.x;
  for (; i < n8; i += stride) {
    const float* p = in + (size_t)i * 8;
    f32x4 f0 = *(const f32x4*)(p);
    f32x4 f1 = *(const f32x4*)(p + 4);
    bf16x8 o;
    o[0] = f2bf(f0[0]); o[1] = f2bf(f0[1]); o[2] = f2bf(f0[2]); o[3] = f2bf(f0[3]);
    o[4] = f2bf(f1[0]); o[5] = f2bf(f1[1]); o[6] = f2bf(f1[2]); o[7] = f2bf(f1[3]);
    *(bf16x8*)(out + (size_t)i * 8) = o;
  }
}

__global__ void cvt_w(const float* __restrict__ w, short* __restrict__ wt) {
  int k = blockIdx.x;
  const float* wk = w + (size_t)k * CDIM * CDIM;
  short* wtk = wt + (size_t)k * CDIM * CDIM;
  for (int t = threadIdx.x; t < CDIM * CDIM; t += blockDim.x) {
    int j = t >> 6, i = t & 63;
    wtk[j * CDIM + i] = f2bf(wk[i * CDIM + j]);
  }
}

// ---- histogram: WG = (k, sub-chunk); LDS-private 1563 bucket bins ----
__global__ __launch_bounds__(256)
void k_hist(const int* __restrict__ om, unsigned int* __restrict__ hist_g) {
  __shared__ unsigned int h[NBKT];
  const int wg = blockIdx.x, tid = threadIdx.x;
  const int k = wg / SUBW, sub = wg - k * SUBW;
  const int pass = k / KPP;
  for (int i = tid; i < NBKT; i += 256) h[i] = 0u;
  __syncthreads();
  const int base = k * MPAIRS + sub * CHUNKH;
  for (int i = tid; i < CHUNKH; i += 256)
    atomicAdd(&h[((unsigned)om[base + i]) >> 7], 1u);
  __syncthreads();
  for (int b = tid; b < NBKT; b += 256)
    hist_g[(size_t)(pass * NBKT + b) * NWGH + wg] = h[b];
}

// ---- 3-kernel exclusive scan over CELLS ([bin][wg] cell-major) ----
__global__ void scan_local(const unsigned int* __restrict__ counts,
                           unsigned int* __restrict__ offsets,
                           unsigned int* __restrict__ bsum, int n) {
  __shared__ unsigned int sh[1024];
  int t = threadIdx.x;
  int idx = blockIdx.x * 1024 + t;
  unsigned int v = (idx < n) ? counts[idx] : 0u;
  sh[t] = v; __syncthreads();
  for (int o = 1; o < 1024; o <<= 1) {
    unsigned int u = (t >= o) ? sh[t - o] : 0u;
    __syncthreads();
    sh[t] += u;
    __syncthreads();
  }
  if (idx < n) offsets[idx] = sh[t] - v;
  if (t == 1023) bsum[blockIdx.x] = sh[1023];
}

__global__ void scan_bsum(unsigned int* __restrict__ bsum, int nb) {
  __shared__ unsigned int sh[1024];
  int t = threadIdx.x;
  unsigned int v = (t < nb) ? bsum[t] : 0u;
  sh[t] = v; __syncthreads();
  for (int o = 1; o < 1024; o <<= 1) {
    unsigned int u = (t >= o) ? sh[t - o] : 0u;
    __syncthreads();
    sh[t] += u;
    __syncthreads();
  }
  if (t < nb) bsum[t] = sh[t] - v;
}

__global__ void scan_apply(unsigned int* __restrict__ offsets,
                           const unsigned int* __restrict__ bsum,
                           const unsigned int* __restrict__ counts, int n) {
  int idx = blockIdx.x * 1024 + threadIdx.x;
  if (idx < n) {
    unsigned int o = offsets[idx] + bsum[blockIdx.x];
    offsets[idx] = o;
    if (idx == n - 1) offsets[n] = o + counts[idx];
  }
}

// ---- scatter 4B entries (outl<<21 | e_local) into (pass,bucket) slots ----
__global__ __launch_bounds__(256)
void k_scatter(const int* __restrict__ om,
               const unsigned int* __restrict__ offs, unsigned int* __restrict__ sorted_g) {
  __shared__ unsigned int cur[NBKT];
  const int wg = blockIdx.x, tid = threadIdx.x;
  const int k = wg / SUBW, sub = wg - k * SUBW;
  const int pass = k / KPP, kk = k - pass * KPP;
  for (int b = tid; b < NBKT; b += 256)
    cur[b] = offs[(size_t)(pass * NBKT + b) * NWGH + wg];
  __syncthreads();
  const int base = k * MPAIRS + sub * CHUNKH;
  const unsigned int elb = (unsigned)(kk * MPAIRS + sub * CHUNKH);
  for (int i = tid; i < CHUNKH; i += 256) {
    unsigned int o = (unsigned)om[base + i];
    unsigned int pos = atomicAdd(&cur[o >> 7], 1u);
    sorted_g[pos] = ((o & 127u) << 21) | (elb + (unsigned)i);
  }
}

// ---- GEMM (per pass): ORIGINAL k-major order, coalesced contrib writes,
// zero atomics. Swapped MFMA: lane (r,h) owns pair base+r,
// channels t*16+h*4+{0..3}. 8 blocks/CU (VGPR=32) for gather MLP. ----
__global__ __launch_bounds__(256, 8)
void k_gemm(const short* __restrict__ a_bf16, const short* __restrict__ wt_bf16,
            const int* __restrict__ in_map, short* __restrict__ contrib, int pass)
{
  const int kk   = blockIdx.y;
  const int k    = pass * KPP + kk;
  const int lane = threadIdx.x & 63;
  const int wave = threadIdx.x >> 6;
  const int r    = lane & 15;
  const int h    = lane >> 4;

  bf16x8 b[4][2];
  const short* wtk = wt_bf16 + (size_t)k * CDIM * CDIM;
#pragma unroll
  for (int t = 0; t < 4; ++t)
#pragma unroll
    for (int c = 0; c < 2; ++c)
      b[t][c] = *(const bf16x8*)(wtk + (t * 16 + r) * CDIM + c * 32 + h * 8);

  const int* imk = in_map + (size_t)k * MPAIRS;
  const int ntiles = MPAIRS / 16;
  const int wstride = gridDim.x * 4;

  for (int tile = blockIdx.x * 4 + wave; tile < ntiles; tile += wstride) {
    const int base = tile * 16;
    const int in_row = imk[base + r];
    const short* arow = a_bf16 + (size_t)in_row * CDIM;
    bf16x8 a0 = *(const bf16x8*)(arow + h * 8);
    bf16x8 a1 = *(const bf16x8*)(arow + 32 + h * 8);

    f32x4 acc[4];
#pragma unroll
    for (int t = 0; t < 4; ++t) {
      acc[t] = (f32x4){0.f, 0.f, 0.f, 0.f};
      acc[t] = __builtin_amdgcn_mfma_f32_16x16x32_bf16(b[t][0], a0, acc[t], 0, 0, 0);
      acc[t] = __builtin_amdgcn_mfma_f32_16x16x32_bf16(b[t][1], a1, acc[t], 0, 0, 0);
    }

    short* crow = contrib + (size_t)(kk * MPAIRS + base + r) * CDIM;
#pragma unroll
    for (int t = 0; t < 4; ++t) {
      short4 s4;
      s4.x = f2bf(acc[t][0]); s4.y = f2bf(acc[t][1]);
      s4.z = f2bf(acc[t][2]); s4.w = f2bf(acc[t][3]);
      *(short4*)(crow + t * 16 + h * 4) = s4;
    }
  }
}

// ---- reduce (per pass): WG(512) per bucket; in-LDS row-sort (parallel scan);
// accumulate: half-wave per row (32 lanes x u32 channel-pairs), 2 rows in
// flight per wave, 4-way entry unroll -> up to 8 outstanding loads. ----
__global__ __launch_bounds__(512, 4)
void k_reduce(const short* __restrict__ contrib,
              const unsigned int* __restrict__ sorted_g,
              const unsigned int* __restrict__ offs,
              float* __restrict__ out, int pass)
{
  __shared__ unsigned int ents[ECAP];
  __shared__ unsigned int h[BROWS], bs[BROWS], cur[BROWS];

  const int bkt = blockIdx.x, tid = threadIdx.x;
  const int bin = pass * NBKT + bkt;
  const unsigned int s = offs[(size_t)bin * NWGH];
  const unsigned int e = offs[(size_t)(bin + 1) * NWGH];
  int cnt = (int)(e - s); if (cnt > ECAP) cnt = ECAP;   // astronomically unlikely clamp

  if (tid < BROWS) h[tid] = 0u;
  __syncthreads();
  for (int i = tid; i < cnt; i += 512)
    atomicAdd(&h[sorted_g[s + i] >> 21], 1u);
  __syncthreads();
  // parallel exclusive scan of h -> bs (Kogge-Stone inclusive, then shift)
  if (tid < BROWS) bs[tid] = h[tid];
  __syncthreads();
#pragma unroll
  for (int o = 1; o < BROWS; o <<= 1) {
    unsigned int v = 0;
    if (tid < BROWS && tid >= o) v = bs[tid - o];
    __syncthreads();
    if (tid < BROWS) bs[tid] += v;
    __syncthreads();
  }
  if (tid < BROWS) {
    unsigned int ex = bs[tid] - h[tid];   // exclusive
    bs[tid] = ex;
    cur[tid] = ex;
  }
  __syncthreads();
  for (int i = tid; i < cnt; i += 512) {
    unsigned int en = sorted_g[s + i];
    unsigned int pos = atomicAdd(&cur[en >> 21], 1u);
    ents[pos] = en;
  }
  __syncthreads();

  const int lane = tid & 63, wv = tid >> 6;            // 8 waves
  const int half = lane >> 5;                          // row parity within pair
  const int cl   = lane & 31;                          // channel pair (2cl, 2cl+1)
  const uint32_t* cb32 = (const uint32_t*)contrib;

#pragma unroll 1
  for (int rp = 0; rp < 8; ++rp) {                     // 8 iters x 2 rows = 16 rows/wave
    const int row  = wv * 16 + rp * 2 + half;
    const int grow = bkt * BROWS + row;
    const bool active = (grow < NROWS) && !(h[row] == 0u && pass);
    float ax = 0.f, ay = 0.f;
    if (active) {
      int j = (int)bs[row];
      const int je = j + (int)h[row];
      float bx = 0.f, by = 0.f, cx = 0.f, cy = 0.f, dx = 0.f, dy = 0.f;
      for (; j + 3 < je; j += 4) {                     // 4-way MLP unroll
        uint32_t w0 = cb32[(size_t)(ents[j]     & 0x1FFFFFu) * 32 + cl];
        uint32_t w1 = cb32[(size_t)(ents[j + 1] & 0x1FFFFFu) * 32 + cl];
        uint32_t w2 = cb32[(size_t)(ents[j + 2] & 0x1FFFFFu) * 32 + cl];
        uint32_t w3 = cb32[(size_t)(ents[j + 3] & 0x1FFFFFu) * 32 + cl];
        ax += bf2f(w0 & 0xFFFFu); ay += bf2f(w0 >> 16);
        bx += bf2f(w1 & 0xFFFFu); by += bf2f(w1 >> 16);
        cx += bf2f(w2 & 0xFFFFu); cy += bf2f(w2 >> 16);
        dx += bf2f(w3 & 0xFFFFu); dy += bf2f(w3 >> 16);
      }
      for (; j < je; ++j) {
        uint32_t w0 = cb32[(size_t)(ents[j] & 0x1FFFFFu) * 32 + cl];
        ax += bf2f(w0 & 0xFFFFu); ay += bf2f(w0 >> 16);
      }
      ax += bx + cx + dx; ay += by + cy + dy;
      float* op = out + (size_t)grow * CDIM + cl * 2;
      if (pass) { float2 prev = *(const float2*)op; ax += prev.x; ay += prev.y; }
      float2 o2; o2.x = ax; o2.y = ay;
      *(float2*)op = o2;
    }
  }
}

extern "C" void kernel_launch(void* const* d_in, const int* in_sizes, int n_in,
                              void* d_out, int out_size, void* d_ws, size_t ws_size,
                              hipStream_t stream) {
  const float* in_feats = (const float*)d_in[0];
  const float* kernel   = (const float*)d_in[1];
  const int*   in_map   = (const int*)d_in[2];
  const int*   out_map  = (const int*)d_in[3];
  float* out = (float*)d_out;

  uint8_t* ws = (uint8_t*)d_ws;
  size_t off = 0;
  auto alloc = [&](size_t bytes) -> void* {
    void* p = ws + off;
    off += (bytes + 255) & ~(size_t)255;
    return p;
  };
  short* in_bf16         = (short*)alloc((size_t)NROWS * CDIM * 2);        // 25.6 MB
  short* wt_bf16         = (short*)alloc((size_t)KVOL * CDIM * CDIM * 2);  // 221 KB
  unsigned int* hist_g   = (unsigned int*)alloc((size_t)CELLS * 4);        // 2.53 MB
  unsigned int* offs     = (unsigned int*)alloc((size_t)(CELLS + 1) * 4);  // 2.53 MB
  unsigned int* bsum     = (unsigned int*)alloc(4096);
  unsigned int* sorted_g = (unsigned int*)alloc((size_t)TOTALC * 4);       // 16.2 MB
  short* contrib         = (short*)alloc((size_t)PASSC * CDIM * 2);        // 172.8 MB

  hipMemsetAsync(hist_g, 0, (size_t)CELLS * 4, stream);

  cvt_feats<<<2048, 256, 0, stream>>>(in_feats, in_bf16, NROWS * CDIM / 8);
  cvt_w<<<KVOL, 256, 0, stream>>>(kernel, wt_bf16);

  k_hist<<<NWGH, 256, 0, stream>>>(out_map, hist_g);

  const int sb = (CELLS + 1023) / 1024;   // 619
  scan_local<<<sb, 1024, 0, stream>>>(hist_g, offs, bsum, CELLS);
  scan_bsum<<<1, 1024, 0, stream>>>(bsum, sb);
  scan_apply<<<sb, 1024, 0, stream>>>(offs, bsum, hist_g, CELLS);

  k_scatter<<<NWGH, 256, 0, stream>>>(out_map, offs, sorted_g);

  for (int p = 0; p < NPASS; ++p) {
    dim3 g(227, KPP);   // 2043 blocks ~= 8/CU capacity, no straggler tail
    k_gemm<<<g, 256, 0, stream>>>(in_bf16, wt_bf16, in_map, contrib, p);
    k_reduce<<<NBKT, 512, 0, stream>>>(contrib, sorted_g, offs, out, p);
  }
}